// Round 1
// baseline (1599.932 us; speedup 1.0000x reference)
//
#include <hip/hip_runtime.h>
#include <hip/hip_bf16.h>

// CustomGNN: 3x GAT layer (4 heads, 64 hid) + BN/ReLU (layers 0,1) + mean-pool + FC.
// All fp32. N=100000 nodes, E=500000 edges, 512 graphs.

#define THREADS 256

__device__ __forceinline__ unsigned fkey(float f) {
    unsigned u = __float_as_uint(f);
    return (u & 0x80000000u) ? ~u : (u | 0x80000000u);
}
__device__ __forceinline__ float funkey(unsigned u) {
    return __uint_as_float((u & 0x80000000u) ? (u & 0x7FFFFFFFu) : ~u);
}

// h = x @ W^T  (x: N x 64, W: 256 x 64, h: N x 256), fused attention projections:
// a_s[n,head] = sum_c h[n,head,c]*att_s[head,c];  a_d likewise.
// Block: 256 threads, each thread owns output column c = tid (head = tid>>6, wave == head).
// 64 rows of x staged in LDS per block.
__global__ __launch_bounds__(THREADS) void k_gemm_att(
    const float* __restrict__ x, const float* __restrict__ W,
    const float* __restrict__ att_s, const float* __restrict__ att_d,
    float* __restrict__ h, float* __restrict__ a_s, float* __restrict__ a_d, int n)
{
    __shared__ float xs[64][64];
    const int tid  = threadIdx.x;
    const int row0 = blockIdx.x * 64;
    const int nrows = min(64, n - row0);

    #pragma unroll
    for (int i = 0; i < 16; ++i) {
        int idx = i * 256 + tid;
        int r = idx >> 6, c = idx & 63;
        xs[r][c] = (r < nrows) ? x[(size_t)(row0 + r) * 64 + c] : 0.f;
    }
    __syncthreads();

    const int c = tid;
    float w[64];
    #pragma unroll
    for (int k4 = 0; k4 < 16; ++k4) {
        float4 v = *(const float4*)(W + (size_t)c * 64 + k4 * 4);
        w[k4*4+0] = v.x; w[k4*4+1] = v.y; w[k4*4+2] = v.z; w[k4*4+3] = v.w;
    }
    const float asw = att_s[c];
    const float adw = att_d[c];
    const int head = tid >> 6;

    for (int r = 0; r < nrows; ++r) {
        float acc = 0.f;
        #pragma unroll
        for (int k = 0; k < 64; ++k) acc = fmaf(xs[r][k], w[k], acc);
        h[(size_t)(row0 + r) * 256 + c] = acc;
        float s = acc * asw;
        float d = acc * adw;
        #pragma unroll
        for (int off = 32; off; off >>= 1) {
            s += __shfl_xor(s, off, 64);
            d += __shfl_xor(d, off, 64);
        }
        if ((tid & 63) == 0) {
            a_s[(size_t)(row0 + r) * 4 + head] = s;
            a_d[(size_t)(row0 + r) * 4 + head] = d;
        }
    }
}

// Per-edge scores: e = LeakyReLU(a_s[row] + a_d[col]); store, atomicMax into emax[col].
__global__ __launch_bounds__(THREADS) void k_score(
    const int* __restrict__ row, const int* __restrict__ col,
    const float* __restrict__ a_s, const float* __restrict__ a_d,
    float* __restrict__ esc, unsigned* __restrict__ emax, int E)
{
    int e = blockIdx.x * THREADS + threadIdx.x;
    if (e >= E) return;
    int r = row[e], c = col[e];
    float4 s = *(const float4*)(a_s + (size_t)r * 4);
    float4 d = *(const float4*)(a_d + (size_t)c * 4);
    float v[4] = { s.x + d.x, s.y + d.y, s.z + d.z, s.w + d.w };
    #pragma unroll
    for (int hh = 0; hh < 4; ++hh) {
        v[hh] = v[hh] >= 0.f ? v[hh] : 0.2f * v[hh];
        atomicMax(emax + (size_t)c * 4 + hh, fkey(v[hh]));
    }
    *(float4*)(esc + (size_t)e * 4) = make_float4(v[0], v[1], v[2], v[3]);
}

// p = exp(e - emax[col]); in-place over esc; atomicAdd into psum[col].
__global__ __launch_bounds__(THREADS) void k_exp(
    const int* __restrict__ col, float* __restrict__ esc,
    const unsigned* __restrict__ emax, float* __restrict__ psum, int E)
{
    int e = blockIdx.x * THREADS + threadIdx.x;
    if (e >= E) return;
    int c = col[e];
    float4 v = *(const float4*)(esc + (size_t)e * 4);
    const unsigned* mp = emax + (size_t)c * 4;
    float p0 = expf(v.x - funkey(mp[0]));
    float p1 = expf(v.y - funkey(mp[1]));
    float p2 = expf(v.z - funkey(mp[2]));
    float p3 = expf(v.w - funkey(mp[3]));
    atomicAdd(psum + (size_t)c * 4 + 0, p0);
    atomicAdd(psum + (size_t)c * 4 + 1, p1);
    atomicAdd(psum + (size_t)c * 4 + 2, p2);
    atomicAdd(psum + (size_t)c * 4 + 3, p3);
    *(float4*)(esc + (size_t)e * 4) = make_float4(p0, p1, p2, p3);
}

// One wave per edge: out[col, c] += 0.25 * sum_h alpha[e,h] * h[row, h, c]
__global__ __launch_bounds__(THREADS) void k_aggr(
    const int* __restrict__ row, const int* __restrict__ col,
    const float* __restrict__ esc, const float* __restrict__ psum,
    const float* __restrict__ h, float* __restrict__ out, int E)
{
    int wid  = (blockIdx.x * THREADS + threadIdx.x) >> 6;
    int lane = threadIdx.x & 63;
    if (wid >= E) return;
    int r = row[wid], c = col[wid];
    float4 p = *(const float4*)(esc + (size_t)wid * 4);
    float4 q = *(const float4*)(psum + (size_t)c * 4);
    float a0 = p.x / (q.x + 1e-8f);
    float a1 = p.y / (q.y + 1e-8f);
    float a2 = p.z / (q.z + 1e-8f);
    float a3 = p.w / (q.w + 1e-8f);
    const float* hb = h + (size_t)r * 256;
    float m = a0 * hb[lane] + a1 * hb[64 + lane] + a2 * hb[128 + lane] + a3 * hb[192 + lane];
    atomicAdd(out + (size_t)c * 64 + lane, 0.25f * m);
}

// BN (eval) + ReLU, in place over (N,64)
__global__ __launch_bounds__(THREADS) void k_bn_relu(
    float* __restrict__ v, const float* __restrict__ gamma, const float* __restrict__ beta,
    const float* __restrict__ mean, const float* __restrict__ var, int n64)
{
    int i = blockIdx.x * THREADS + threadIdx.x;
    if (i >= n64) return;
    int c = i & 63;
    float y = (v[i] - mean[c]) * (1.0f / sqrtf(var[c] + 1e-5f)) * gamma[c] + beta[c];
    v[i] = y > 0.f ? y : 0.f;
}

// One wave per node: sums[g] += x[n], cnt[g] += 1
__global__ __launch_bounds__(THREADS) void k_pool(
    const float* __restrict__ xf, const int* __restrict__ batch,
    float* __restrict__ sums, float* __restrict__ cnt, int n)
{
    int wid  = (blockIdx.x * THREADS + threadIdx.x) >> 6;
    int lane = threadIdx.x & 63;
    if (wid >= n) return;
    int g = batch[wid];
    atomicAdd(sums + (size_t)g * 64 + lane, xf[(size_t)wid * 64 + lane]);
    if (lane == 0) atomicAdd(cnt + g, 1.f);
}

// out[g, j] = sum_c (sums[g,c]/max(cnt,1)) * fc_w[j,c] + fc_b[j]
__global__ __launch_bounds__(THREADS) void k_fc(
    const float* __restrict__ sums, const float* __restrict__ cnt,
    const float* __restrict__ fw, const float* __restrict__ fb,
    float* __restrict__ out, int G)
{
    int g = blockIdx.x * THREADS + threadIdx.x;
    if (g >= G) return;
    float cdiv = fmaxf(cnt[g], 1.f);
    float o0 = fb[0], o1 = fb[1];
    for (int k = 0; k < 64; ++k) {
        float p = sums[(size_t)g * 64 + k] / cdiv;
        o0 = fmaf(p, fw[k], o0);
        o1 = fmaf(p, fw[64 + k], o1);
    }
    out[(size_t)g * 2 + 0] = o0;
    out[(size_t)g * 2 + 1] = o1;
}

static inline size_t align256(size_t x) { return (x + 255) & ~(size_t)255; }

extern "C" void kernel_launch(void* const* d_in, const int* in_sizes, int n_in,
                              void* d_out, int out_size, void* d_ws, size_t ws_size,
                              hipStream_t stream)
{
    const float* x        = (const float*)d_in[0];
    const int*   eidx     = (const int*)d_in[1];
    const int*   batch    = (const int*)d_in[2];
    const float* Ws       = (const float*)d_in[3];
    const float* att_src  = (const float*)d_in[4];
    const float* att_dst  = (const float*)d_in[5];
    const float* bn_gamma = (const float*)d_in[6];
    const float* bn_beta  = (const float*)d_in[7];
    const float* bn_mean  = (const float*)d_in[8];
    const float* bn_var   = (const float*)d_in[9];
    const float* fc_w     = (const float*)d_in[10];
    const float* fc_b     = (const float*)d_in[11];

    const int N = in_sizes[0] / 64;
    const int E = in_sizes[1] / 2;
    const int G = 512;

    const int* row = eidx;
    const int* col = eidx + E;

    // workspace layout (~168 MB)
    char* p = (char*)d_ws;
    float*    h    = (float*)p;    p += align256((size_t)N * 256 * 4);
    float*    a_s  = (float*)p;    p += align256((size_t)N * 4 * 4);
    float*    a_d  = (float*)p;    p += align256((size_t)N * 4 * 4);
    unsigned* emax = (unsigned*)p; p += align256((size_t)N * 4 * 4);
    float*    psum = (float*)p;    p += align256((size_t)N * 4 * 4);
    float*    esc  = (float*)p;    p += align256((size_t)E * 4 * 4);
    float*    xb0  = (float*)p;    p += align256((size_t)N * 64 * 4);
    float*    xb1  = (float*)p;    p += align256((size_t)N * 64 * 4);
    float*    sums = (float*)p;    p += align256((size_t)G * 64 * 4);
    float*    cnt  = (float*)p;    p += align256((size_t)G * 4);
    (void)ws_size; (void)n_in; (void)out_size;

    const float* xin = x;
    for (int l = 0; l < 3; ++l) {
        float* xout = (l == 1) ? xb1 : xb0;
        hipMemsetAsync(emax, 0, (size_t)N * 4 * 4, stream);
        hipMemsetAsync(psum, 0, (size_t)N * 4 * 4, stream);
        hipMemsetAsync(xout, 0, (size_t)N * 64 * 4, stream);

        k_gemm_att<<<(N + 63) / 64, THREADS, 0, stream>>>(
            xin, Ws + (size_t)l * 256 * 64, att_src + (size_t)l * 256,
            att_dst + (size_t)l * 256, h, a_s, a_d, N);
        k_score<<<(E + THREADS - 1) / THREADS, THREADS, 0, stream>>>(
            row, col, a_s, a_d, esc, emax, E);
        k_exp<<<(E + THREADS - 1) / THREADS, THREADS, 0, stream>>>(
            col, esc, emax, psum, E);
        k_aggr<<<(E + 3) / 4, THREADS, 0, stream>>>(
            row, col, esc, psum, h, xout, E);
        if (l < 2) {
            k_bn_relu<<<((size_t)N * 64 + THREADS - 1) / THREADS, THREADS, 0, stream>>>(
                xout, bn_gamma + l * 64, bn_beta + l * 64, bn_mean + l * 64, bn_var + l * 64, N * 64);
        }
        xin = xout;
    }

    hipMemsetAsync(sums, 0, (size_t)G * 64 * 4, stream);
    hipMemsetAsync(cnt, 0, (size_t)G * 4, stream);
    k_pool<<<(N + 3) / 4, THREADS, 0, stream>>>(xin, batch, sums, cnt, N);
    k_fc<<<(G + THREADS - 1) / THREADS, THREADS, 0, stream>>>(
        sums, cnt, fc_w, fc_b, (float*)d_out, G);
}

// Round 2
// 832.083 us; speedup vs baseline: 1.9228x; 1.9228x over previous
//
#include <hip/hip_runtime.h>

// CustomGNN: 3x GAT layer (4 heads, 64 hid) + BN/ReLU (layers 0,1) + mean-pool + FC.
// All fp32. N=100000 nodes, E=500000 edges, 512 graphs.
// Strategy: counting-sort edges by dst once -> CSR; per layer one fused GEMM+att
// kernel and one gather-based GAT kernel (no scatter atomics). BN/ReLU fused
// into the next layer's GEMM load. Segmented pool (batch is sorted).

#define THREADS 256

// ---------------- GEMM + attention projections (+ fused BN/ReLU on input) ----
// h = bnrelu(x) @ W^T  (N x 64 -> N x 256), a_s[n,h]=<h_nh, att_s_h>, a_d likewise.
// Block: 256 threads; thread owns output column c=tid (head = tid>>6). 64 rows/block.
__global__ __launch_bounds__(THREADS) void k_gemm_att(
    const float* __restrict__ x, const float* __restrict__ W,
    const float* __restrict__ att_s, const float* __restrict__ att_d,
    const float* __restrict__ bng, const float* __restrict__ bnb,
    const float* __restrict__ bnm, const float* __restrict__ bnv, int use_bn,
    float* __restrict__ h, float* __restrict__ a_s, float* __restrict__ a_d, int n)
{
    __shared__ float xs[64][64];
    const int tid  = threadIdx.x;
    const int row0 = blockIdx.x * 64;
    const int nrows = min(64, n - row0);
    const int cc = tid & 63;

    float scale = 1.f, shift = 0.f;
    if (use_bn) {
        scale = bng[cc] * rsqrtf(bnv[cc] + 1e-5f);
        shift = bnb[cc] - bnm[cc] * scale;
    }

    #pragma unroll
    for (int i = 0; i < 16; ++i) {
        int idx = i * 256 + tid;
        int r = idx >> 6;
        float val = 0.f;
        if (r < nrows) {
            val = x[(size_t)(row0 + r) * 64 + cc];
            if (use_bn) { val = fmaf(val, scale, shift); val = fmaxf(val, 0.f); }
        }
        xs[r][cc] = val;
    }
    __syncthreads();

    const int c = tid;
    float w[64];
    #pragma unroll
    for (int k4 = 0; k4 < 16; ++k4) {
        float4 v = *(const float4*)(W + (size_t)c * 64 + k4 * 4);
        w[k4*4+0] = v.x; w[k4*4+1] = v.y; w[k4*4+2] = v.z; w[k4*4+3] = v.w;
    }
    const float asw = att_s[c];
    const float adw = att_d[c];
    const int head = tid >> 6;

    for (int r = 0; r < nrows; ++r) {
        float acc = 0.f;
        #pragma unroll
        for (int k = 0; k < 64; ++k) acc = fmaf(xs[r][k], w[k], acc);
        h[(size_t)(row0 + r) * 256 + c] = acc;
        float s = acc * asw;
        float d = acc * adw;
        #pragma unroll
        for (int off = 32; off; off >>= 1) {
            s += __shfl_xor(s, off, 64);
            d += __shfl_xor(d, off, 64);
        }
        if ((tid & 63) == 0) {
            a_s[(size_t)(row0 + r) * 4 + head] = s;
            a_d[(size_t)(row0 + r) * 4 + head] = d;
        }
    }
}

// ---------------- counting sort of edges by destination --------------------
__global__ __launch_bounds__(THREADS) void k_hist(
    const int* __restrict__ col, int* __restrict__ hist, int E)
{
    int e = blockIdx.x * THREADS + threadIdx.x;
    if (e < E) atomicAdd(hist + col[e], 1);
}

__global__ __launch_bounds__(THREADS) void k_scan1(
    const int* __restrict__ hist, int* __restrict__ offs, int* __restrict__ partials, int n)
{
    __shared__ int buf0[256], buf1[256];
    int tid = threadIdx.x;
    int i = blockIdx.x * 256 + tid;
    int v = (i < n) ? hist[i] : 0;
    buf0[tid] = v;
    __syncthreads();
    int* src = buf0; int* dst = buf1;
    #pragma unroll
    for (int off = 1; off < 256; off <<= 1) {
        int t = src[tid];
        if (tid >= off) t += src[tid - off];
        dst[tid] = t;
        __syncthreads();
        int* tmp = src; src = dst; dst = tmp;
    }
    if (i < n) offs[i] = src[tid] - v;
    if (tid == 255) partials[blockIdx.x] = src[255];
}

__global__ __launch_bounds__(512) void k_scan2(int* __restrict__ partials, int nb)
{
    __shared__ int buf0[512], buf1[512];
    int tid = threadIdx.x;
    int v = (tid < nb) ? partials[tid] : 0;
    buf0[tid] = v;
    __syncthreads();
    int* src = buf0; int* dst = buf1;
    #pragma unroll
    for (int off = 1; off < 512; off <<= 1) {
        int t = src[tid];
        if (tid >= off) t += src[tid - off];
        dst[tid] = t;
        __syncthreads();
        int* tmp = src; src = dst; dst = tmp;
    }
    if (tid < nb) partials[tid] = src[tid] - v;
}

__global__ __launch_bounds__(THREADS) void k_scan3(
    int* __restrict__ offs, const int* __restrict__ partials, int n)
{
    int i = blockIdx.x * THREADS + threadIdx.x;
    if (i < n) offs[i] += partials[i >> 8];
}

__global__ __launch_bounds__(THREADS) void k_scatter(
    const int* __restrict__ row, const int* __restrict__ col,
    const int* __restrict__ offs, int* __restrict__ tmpc,
    int* __restrict__ rs, int E)
{
    int e = blockIdx.x * THREADS + threadIdx.x;
    if (e >= E) return;
    int c = col[e];
    int pos = offs[c] + atomicAdd(tmpc + c, 1);
    rs[pos] = row[e];
}

// ---------------- fused gather-based GAT aggregation -----------------------
// One wave per destination node; lane = channel. Two passes over the node's
// in-edges: (1) per-head running max, (2) recompute score, p=exp(s-max),
// accumulate per-head weighted h and p-sums; normalize once.
__global__ __launch_bounds__(THREADS) void k_gat(
    const int* __restrict__ rs, const int* __restrict__ offs, const int* __restrict__ deg,
    const float* __restrict__ a_s, const float* __restrict__ a_d,
    const float* __restrict__ h, float* __restrict__ out, int n)
{
    int wid  = (blockIdx.x * THREADS + threadIdx.x) >> 6;
    int lane = threadIdx.x & 63;
    if (wid >= n) return;
    const int start = offs[wid];
    const int d     = deg[wid];
    const float4 ad = *(const float4*)(a_d + (size_t)wid * 4);

    float m0 = -1e30f, m1 = -1e30f, m2 = -1e30f, m3 = -1e30f;
    for (int i = 0; i < d; ++i) {
        int r = rs[start + i];
        float4 as = *(const float4*)(a_s + (size_t)r * 4);
        float v0 = as.x + ad.x, v1 = as.y + ad.y, v2 = as.z + ad.z, v3 = as.w + ad.w;
        v0 = v0 >= 0.f ? v0 : 0.2f * v0;
        v1 = v1 >= 0.f ? v1 : 0.2f * v1;
        v2 = v2 >= 0.f ? v2 : 0.2f * v2;
        v3 = v3 >= 0.f ? v3 : 0.2f * v3;
        m0 = fmaxf(m0, v0); m1 = fmaxf(m1, v1); m2 = fmaxf(m2, v2); m3 = fmaxf(m3, v3);
    }

    float acc0 = 0.f, acc1 = 0.f, acc2 = 0.f, acc3 = 0.f;
    float ps0 = 0.f, ps1 = 0.f, ps2 = 0.f, ps3 = 0.f;
    for (int i = 0; i < d; ++i) {
        int r = rs[start + i];
        float4 as = *(const float4*)(a_s + (size_t)r * 4);
        float v0 = as.x + ad.x, v1 = as.y + ad.y, v2 = as.z + ad.z, v3 = as.w + ad.w;
        v0 = v0 >= 0.f ? v0 : 0.2f * v0;
        v1 = v1 >= 0.f ? v1 : 0.2f * v1;
        v2 = v2 >= 0.f ? v2 : 0.2f * v2;
        v3 = v3 >= 0.f ? v3 : 0.2f * v3;
        float p0 = __expf(v0 - m0), p1 = __expf(v1 - m1);
        float p2 = __expf(v2 - m2), p3 = __expf(v3 - m3);
        ps0 += p0; ps1 += p1; ps2 += p2; ps3 += p3;
        const float* hb = h + (size_t)r * 256;
        acc0 = fmaf(p0, hb[lane],       acc0);
        acc1 = fmaf(p1, hb[64 + lane],  acc1);
        acc2 = fmaf(p2, hb[128 + lane], acc2);
        acc3 = fmaf(p3, hb[192 + lane], acc3);
    }
    float o = acc0 / (ps0 + 1e-8f) + acc1 / (ps1 + 1e-8f)
            + acc2 / (ps2 + 1e-8f) + acc3 / (ps3 + 1e-8f);
    out[(size_t)wid * 64 + lane] = 0.25f * o;
}

// ---------------- segmented mean pool (batch sorted) -----------------------
#define POOL_CHUNK 32
__global__ __launch_bounds__(THREADS) void k_pool(
    const float* __restrict__ xf, const int* __restrict__ batch,
    float* __restrict__ sums, float* __restrict__ cnt, int n)
{
    int wid  = (blockIdx.x * THREADS + threadIdx.x) >> 6;
    int lane = threadIdx.x & 63;
    int n0 = wid * POOL_CHUNK;
    if (n0 >= n) return;
    int n1 = min(n0 + POOL_CHUNK, n);
    int g = batch[n0];
    float acc = 0.f, c = 0.f;
    for (int i = n0; i < n1; ++i) {
        int gi = batch[i];
        if (gi != g) {
            atomicAdd(sums + (size_t)g * 64 + lane, acc);
            if (lane == 0) atomicAdd(cnt + g, c);
            g = gi; acc = 0.f; c = 0.f;
        }
        acc += xf[(size_t)i * 64 + lane];
        c += 1.f;
    }
    atomicAdd(sums + (size_t)g * 64 + lane, acc);
    if (lane == 0) atomicAdd(cnt + g, c);
}

__global__ __launch_bounds__(THREADS) void k_fc(
    const float* __restrict__ sums, const float* __restrict__ cnt,
    const float* __restrict__ fw, const float* __restrict__ fb,
    float* __restrict__ out, int G)
{
    int g = blockIdx.x * THREADS + threadIdx.x;
    if (g >= G) return;
    float cdiv = fmaxf(cnt[g], 1.f);
    float o0 = fb[0], o1 = fb[1];
    for (int k = 0; k < 64; ++k) {
        float p = sums[(size_t)g * 64 + k] / cdiv;
        o0 = fmaf(p, fw[k], o0);
        o1 = fmaf(p, fw[64 + k], o1);
    }
    out[(size_t)g * 2 + 0] = o0;
    out[(size_t)g * 2 + 1] = o1;
}

static inline size_t align256(size_t x) { return (x + 255) & ~(size_t)255; }

extern "C" void kernel_launch(void* const* d_in, const int* in_sizes, int n_in,
                              void* d_out, int out_size, void* d_ws, size_t ws_size,
                              hipStream_t stream)
{
    const float* x        = (const float*)d_in[0];
    const int*   eidx     = (const int*)d_in[1];
    const int*   batch    = (const int*)d_in[2];
    const float* Ws       = (const float*)d_in[3];
    const float* att_src  = (const float*)d_in[4];
    const float* att_dst  = (const float*)d_in[5];
    const float* bn_gamma = (const float*)d_in[6];
    const float* bn_beta  = (const float*)d_in[7];
    const float* bn_mean  = (const float*)d_in[8];
    const float* bn_var   = (const float*)d_in[9];
    const float* fc_w     = (const float*)d_in[10];
    const float* fc_b     = (const float*)d_in[11];

    const int N = in_sizes[0] / 64;
    const int E = in_sizes[1] / 2;
    const int G = 512;
    const int* row = eidx;
    const int* col = eidx + E;

    char* p = (char*)d_ws;
    float* h    = (float*)p; p += align256((size_t)N * 256 * 4);
    float* a_s  = (float*)p; p += align256((size_t)N * 4 * 4);
    float* a_d  = (float*)p; p += align256((size_t)N * 4 * 4);
    float* xb0  = (float*)p; p += align256((size_t)N * 64 * 4);
    float* xb1  = (float*)p; p += align256((size_t)N * 64 * 4);
    int*   hist = (int*)p;   p += align256((size_t)N * 4);
    int*   offs = (int*)p;   p += align256((size_t)N * 4);
    int*   tmpc = (int*)p;   p += align256((size_t)N * 4);
    int*   part = (int*)p;   p += align256((size_t)1024 * 4);
    int*   rs   = (int*)p;   p += align256((size_t)E * 4);
    float* sums = (float*)p; p += align256((size_t)G * 64 * 4);
    float* cnt  = (float*)p; p += align256((size_t)G * 4);
    (void)ws_size; (void)n_in; (void)out_size;

    const int nb = (N + 255) / 256;

    // ---- build CSR (by destination) once per call ----
    hipMemsetAsync(hist, 0, (size_t)N * 4, stream);
    hipMemsetAsync(tmpc, 0, (size_t)N * 4, stream);
    k_hist<<<(E + THREADS - 1) / THREADS, THREADS, 0, stream>>>(col, hist, E);
    k_scan1<<<nb, THREADS, 0, stream>>>(hist, offs, part, N);
    k_scan2<<<1, 512, 0, stream>>>(part, nb);
    k_scan3<<<nb, THREADS, 0, stream>>>(offs, part, N);
    k_scatter<<<(E + THREADS - 1) / THREADS, THREADS, 0, stream>>>(row, col, offs, tmpc, rs, E);

    // ---- 3 GAT layers ----
    const float* xin = x;
    for (int l = 0; l < 3; ++l) {
        float* xout = (l == 1) ? xb1 : xb0;
        k_gemm_att<<<(N + 63) / 64, THREADS, 0, stream>>>(
            xin, Ws + (size_t)l * 256 * 64, att_src + (size_t)l * 256, att_dst + (size_t)l * 256,
            bn_gamma + (l - 1) * 64, bn_beta + (l - 1) * 64,
            bn_mean + (l - 1) * 64, bn_var + (l - 1) * 64, (l > 0) ? 1 : 0,
            h, a_s, a_d, N);
        k_gat<<<(N * 64 + THREADS - 1) / THREADS, THREADS, 0, stream>>>(
            rs, offs, hist, a_s, a_d, h, xout, N);
        xin = xout;
    }

    // ---- pool + fc ----
    hipMemsetAsync(sums, 0, (size_t)G * 64 * 4, stream);
    hipMemsetAsync(cnt, 0, (size_t)G * 4, stream);
    int pool_waves = (N + POOL_CHUNK - 1) / POOL_CHUNK;
    k_pool<<<(pool_waves * 64 + THREADS - 1) / THREADS, THREADS, 0, stream>>>(
        xin, batch, sums, cnt, N);
    k_fc<<<(G + THREADS - 1) / THREADS, THREADS, 0, stream>>>(
        sums, cnt, fc_w, fc_b, (float*)d_out, G);
}

// Round 3
// 811.056 us; speedup vs baseline: 1.9727x; 1.0259x over previous
//
#include <hip/hip_runtime.h>

// CustomGNN: 3x GAT layer (4 heads, 64 hid) + BN/ReLU (layers 0,1) + mean-pool + FC.
// All fp32. N=100000, E=500000, G=512.
// R2: attention projections folded to k-space (no shuffles in GEMM); alpha
// precomputed per-edge (k_gat single pass); BN/ReLU fused into k_gat epilogue.

#define THREADS 256
#define XS_PAD 68   // 68*4=272 bytes, 16B-aligned rows for b128 broadcast reads

// ---- prep: fold[l][sd][head][k] = sum_c W[l][head*64+c][k] * att[l][head*64+c]
__global__ __launch_bounds__(THREADS) void k_prep(
    const float* __restrict__ Ws, const float* __restrict__ att_src,
    const float* __restrict__ att_dst, float* __restrict__ fold)
{
    int idx = blockIdx.x * THREADS + threadIdx.x;
    if (idx >= 3 * 2 * 4 * 64) return;
    int k = idx & 63, head = (idx >> 6) & 3, sd = (idx >> 8) & 1, l = idx >> 9;
    const float* att = (sd ? att_dst : att_src) + l * 256 + head * 64;
    const float* Wb  = Ws + (size_t)l * 16384 + (size_t)head * 64 * 64;
    float s = 0.f;
    #pragma unroll
    for (int c = 0; c < 64; ++c) s = fmaf(Wb[(size_t)c * 64 + k], att[c], s);
    fold[((l * 2 + sd) * 4 + head) * 64 + k] = s;
}

// ---- pure GEMM h = x' @ W^T  + epilogue a_s/a_d dots (from folded vectors)
__global__ __launch_bounds__(THREADS) void k_gemm_att(
    const float* __restrict__ x, const float* __restrict__ W,
    const float* __restrict__ fold_l,   // [8][64]: vec 0-3 = As heads, 4-7 = Ad heads
    float* __restrict__ h, float* __restrict__ a_s, float* __restrict__ a_d, int n)
{
    __shared__ float xs[64][XS_PAD];
    __shared__ float sfold[512];
    const int tid  = threadIdx.x;
    const int row0 = blockIdx.x * 64;
    const int nrows = min(64, n - row0);

    sfold[tid] = fold_l[tid];
    sfold[tid + 256] = fold_l[tid + 256];

    #pragma unroll
    for (int i = 0; i < 16; ++i) {
        int idx = i * 256 + tid;
        int r = idx >> 6, k = idx & 63;
        xs[r][k] = (r < nrows) ? x[(size_t)(row0 + r) * 64 + k] : 0.f;
    }
    __syncthreads();

    const int c = tid;
    float w[64];
    #pragma unroll
    for (int k4 = 0; k4 < 16; ++k4) {
        float4 v = *(const float4*)(W + (size_t)c * 64 + k4 * 4);
        w[k4*4+0] = v.x; w[k4*4+1] = v.y; w[k4*4+2] = v.z; w[k4*4+3] = v.w;
    }

    for (int r = 0; r < nrows; ++r) {
        float acc = 0.f;
        #pragma unroll
        for (int k = 0; k < 64; ++k) acc = fmaf(xs[r][k], w[k], acc);
        h[(size_t)(row0 + r) * 256 + c] = acc;
    }

    // epilogue: 512 dot-products (64 rows x 8 vecs), 2 per thread, no shuffles
    #pragma unroll
    for (int j = 0; j < 2; ++j) {
        int s = tid + j * 256;
        int rr = s & 63, vec = s >> 6;           // vec uniform per wave
        float acc = 0.f;
        #pragma unroll
        for (int k = 0; k < 64; ++k) acc = fmaf(xs[rr][k], sfold[vec * 64 + k], acc);
        if (rr < nrows) {
            if (vec < 4) a_s[(size_t)(row0 + rr) * 4 + vec] = acc;
            else         a_d[(size_t)(row0 + rr) * 4 + (vec - 4)] = acc;
        }
    }
}

// ---------------- counting sort of edges by destination --------------------
__global__ __launch_bounds__(THREADS) void k_hist(
    const int* __restrict__ col, int* __restrict__ hist, int E)
{
    int e = blockIdx.x * THREADS + threadIdx.x;
    if (e < E) atomicAdd(hist + col[e], 1);
}

__global__ __launch_bounds__(THREADS) void k_scan1(
    const int* __restrict__ hist, int* __restrict__ offs, int* __restrict__ partials, int n)
{
    __shared__ int buf0[256], buf1[256];
    int tid = threadIdx.x;
    int i = blockIdx.x * 256 + tid;
    int v = (i < n) ? hist[i] : 0;
    buf0[tid] = v;
    __syncthreads();
    int* src = buf0; int* dst = buf1;
    #pragma unroll
    for (int off = 1; off < 256; off <<= 1) {
        int t = src[tid];
        if (tid >= off) t += src[tid - off];
        dst[tid] = t;
        __syncthreads();
        int* tmp = src; src = dst; dst = tmp;
    }
    if (i < n) offs[i] = src[tid] - v;
    if (tid == 255) partials[blockIdx.x] = src[255];
}

__global__ __launch_bounds__(512) void k_scan2(int* __restrict__ partials, int nb)
{
    __shared__ int buf0[512], buf1[512];
    int tid = threadIdx.x;
    int v = (tid < nb) ? partials[tid] : 0;
    buf0[tid] = v;
    __syncthreads();
    int* src = buf0; int* dst = buf1;
    #pragma unroll
    for (int off = 1; off < 512; off <<= 1) {
        int t = src[tid];
        if (tid >= off) t += src[tid - off];
        dst[tid] = t;
        __syncthreads();
        int* tmp = src; src = dst; dst = tmp;
    }
    if (tid < nb) partials[tid] = src[tid] - v;
}

__global__ __launch_bounds__(THREADS) void k_scan3(
    int* __restrict__ offs, const int* __restrict__ partials, int n)
{
    int i = blockIdx.x * THREADS + threadIdx.x;
    if (i < n) offs[i] += partials[i >> 8];
}

__global__ __launch_bounds__(THREADS) void k_scatter(
    const int* __restrict__ row, const int* __restrict__ col,
    const int* __restrict__ offs, int* __restrict__ tmpc,
    int* __restrict__ rs, int E)
{
    int e = blockIdx.x * THREADS + threadIdx.x;
    if (e >= E) return;
    int c = col[e];
    int pos = offs[c] + atomicAdd(tmpc + c, 1);
    rs[pos] = row[e];
}

// ---- per-node alpha: thread per dst node; 3 tiny passes over its edges
__global__ __launch_bounds__(THREADS) void k_alpha(
    const int* __restrict__ rs, const int* __restrict__ offs, const int* __restrict__ deg,
    const float* __restrict__ a_s, const float* __restrict__ a_d,
    float* __restrict__ alpha, int n)
{
    int v = blockIdx.x * THREADS + threadIdx.x;
    if (v >= n) return;
    const int start = offs[v];
    const int d     = deg[v];
    const float4 ad = *(const float4*)(a_d + (size_t)v * 4);

    float m0 = -1e30f, m1 = -1e30f, m2 = -1e30f, m3 = -1e30f;
    for (int i = 0; i < d; ++i) {
        int r = rs[start + i];
        float4 as = *(const float4*)(a_s + (size_t)r * 4);
        float v0 = as.x + ad.x, v1 = as.y + ad.y, v2 = as.z + ad.z, v3 = as.w + ad.w;
        v0 = v0 >= 0.f ? v0 : 0.2f * v0;
        v1 = v1 >= 0.f ? v1 : 0.2f * v1;
        v2 = v2 >= 0.f ? v2 : 0.2f * v2;
        v3 = v3 >= 0.f ? v3 : 0.2f * v3;
        *(float4*)(alpha + (size_t)(start + i) * 4) = make_float4(v0, v1, v2, v3);
        m0 = fmaxf(m0, v0); m1 = fmaxf(m1, v1); m2 = fmaxf(m2, v2); m3 = fmaxf(m3, v3);
    }
    float ps0 = 0.f, ps1 = 0.f, ps2 = 0.f, ps3 = 0.f;
    for (int i = 0; i < d; ++i) {
        float4 s = *(const float4*)(alpha + (size_t)(start + i) * 4);
        float p0 = __expf(s.x - m0), p1 = __expf(s.y - m1);
        float p2 = __expf(s.z - m2), p3 = __expf(s.w - m3);
        ps0 += p0; ps1 += p1; ps2 += p2; ps3 += p3;
        *(float4*)(alpha + (size_t)(start + i) * 4) = make_float4(p0, p1, p2, p3);
    }
    float i0 = 0.25f / (ps0 + 1e-8f), i1 = 0.25f / (ps1 + 1e-8f);
    float i2 = 0.25f / (ps2 + 1e-8f), i3 = 0.25f / (ps3 + 1e-8f);
    for (int i = 0; i < d; ++i) {
        float4 s = *(const float4*)(alpha + (size_t)(start + i) * 4);
        *(float4*)(alpha + (size_t)(start + i) * 4) =
            make_float4(s.x * i0, s.y * i1, s.z * i2, s.w * i3);
    }
}

// ---- single-pass gather aggregation; wave per node, lane = channel; fused BN/ReLU
__global__ __launch_bounds__(THREADS) void k_gat(
    const int* __restrict__ rs, const int* __restrict__ offs, const int* __restrict__ deg,
    const float* __restrict__ alpha, const float* __restrict__ h,
    const float* __restrict__ bng, const float* __restrict__ bnb,
    const float* __restrict__ bnm, const float* __restrict__ bnv, int use_bn,
    float* __restrict__ out, int n)
{
    int wid  = (blockIdx.x * THREADS + threadIdx.x) >> 6;
    int lane = threadIdx.x & 63;
    if (wid >= n) return;
    const int start = offs[wid];
    const int d     = deg[wid];

    float acc = 0.f;
    for (int i = 0; i < d; ++i) {
        int r = rs[start + i];
        float4 a = *(const float4*)(alpha + (size_t)(start + i) * 4);
        const float* hb = h + (size_t)r * 256;
        acc = fmaf(a.x, hb[lane],       acc);
        acc = fmaf(a.y, hb[64 + lane],  acc);
        acc = fmaf(a.z, hb[128 + lane], acc);
        acc = fmaf(a.w, hb[192 + lane], acc);
    }
    if (use_bn) {
        float scale = bng[lane] * rsqrtf(bnv[lane] + 1e-5f);
        float shift = bnb[lane] - bnm[lane] * scale;
        acc = fmaxf(fmaf(acc, scale, shift), 0.f);
    }
    out[(size_t)wid * 64 + lane] = acc;
}

// ---- segmented mean pool (batch sorted) ----
#define POOL_CHUNK 32
__global__ __launch_bounds__(THREADS) void k_pool(
    const float* __restrict__ xf, const int* __restrict__ batch,
    float* __restrict__ sums, float* __restrict__ cnt, int n)
{
    int wid  = (blockIdx.x * THREADS + threadIdx.x) >> 6;
    int lane = threadIdx.x & 63;
    int n0 = wid * POOL_CHUNK;
    if (n0 >= n) return;
    int n1 = min(n0 + POOL_CHUNK, n);
    int g = batch[n0];
    float acc = 0.f, c = 0.f;
    for (int i = n0; i < n1; ++i) {
        int gi = batch[i];
        if (gi != g) {
            atomicAdd(sums + (size_t)g * 64 + lane, acc);
            if (lane == 0) atomicAdd(cnt + g, c);
            g = gi; acc = 0.f; c = 0.f;
        }
        acc += xf[(size_t)i * 64 + lane];
        c += 1.f;
    }
    atomicAdd(sums + (size_t)g * 64 + lane, acc);
    if (lane == 0) atomicAdd(cnt + g, c);
}

__global__ __launch_bounds__(THREADS) void k_fc(
    const float* __restrict__ sums, const float* __restrict__ cnt,
    const float* __restrict__ fw, const float* __restrict__ fb,
    float* __restrict__ out, int G)
{
    int g = blockIdx.x * THREADS + threadIdx.x;
    if (g >= G) return;
    float cdiv = fmaxf(cnt[g], 1.f);
    float o0 = fb[0], o1 = fb[1];
    for (int k = 0; k < 64; ++k) {
        float p = sums[(size_t)g * 64 + k] / cdiv;
        o0 = fmaf(p, fw[k], o0);
        o1 = fmaf(p, fw[64 + k], o1);
    }
    out[(size_t)g * 2 + 0] = o0;
    out[(size_t)g * 2 + 1] = o1;
}

static inline size_t align256(size_t x) { return (x + 255) & ~(size_t)255; }

extern "C" void kernel_launch(void* const* d_in, const int* in_sizes, int n_in,
                              void* d_out, int out_size, void* d_ws, size_t ws_size,
                              hipStream_t stream)
{
    const float* x        = (const float*)d_in[0];
    const int*   eidx     = (const int*)d_in[1];
    const int*   batch    = (const int*)d_in[2];
    const float* Ws       = (const float*)d_in[3];
    const float* att_src  = (const float*)d_in[4];
    const float* att_dst  = (const float*)d_in[5];
    const float* bn_gamma = (const float*)d_in[6];
    const float* bn_beta  = (const float*)d_in[7];
    const float* bn_mean  = (const float*)d_in[8];
    const float* bn_var   = (const float*)d_in[9];
    const float* fc_w     = (const float*)d_in[10];
    const float* fc_b     = (const float*)d_in[11];

    const int N = in_sizes[0] / 64;
    const int E = in_sizes[1] / 2;
    const int G = 512;
    const int* row = eidx;
    const int* col = eidx + E;

    char* p = (char*)d_ws;
    float* h     = (float*)p; p += align256((size_t)N * 256 * 4);
    float* a_s   = (float*)p; p += align256((size_t)N * 4 * 4);
    float* a_d   = (float*)p; p += align256((size_t)N * 4 * 4);
    float* xb0   = (float*)p; p += align256((size_t)N * 64 * 4);
    float* xb1   = (float*)p; p += align256((size_t)N * 64 * 4);
    int*   hist  = (int*)p;   p += align256((size_t)N * 4);
    int*   offs  = (int*)p;   p += align256((size_t)N * 4);
    int*   tmpc  = (int*)p;   p += align256((size_t)N * 4);
    int*   part  = (int*)p;   p += align256((size_t)1024 * 4);
    int*   rs    = (int*)p;   p += align256((size_t)E * 4);
    float* alpha = (float*)p; p += align256((size_t)E * 4 * 4);
    float* fold  = (float*)p; p += align256((size_t)1536 * 4);
    float* sums  = (float*)p; p += align256((size_t)G * 64 * 4);
    float* cnt   = (float*)p; p += align256((size_t)G * 4);
    (void)ws_size; (void)n_in; (void)out_size;

    const int nb = (N + 255) / 256;

    // ---- prep folded attention vectors + CSR by destination ----
    k_prep<<<6, THREADS, 0, stream>>>(Ws, att_src, att_dst, fold);
    hipMemsetAsync(hist, 0, (size_t)N * 4, stream);
    hipMemsetAsync(tmpc, 0, (size_t)N * 4, stream);
    k_hist<<<(E + THREADS - 1) / THREADS, THREADS, 0, stream>>>(col, hist, E);
    k_scan1<<<nb, THREADS, 0, stream>>>(hist, offs, part, N);
    k_scan2<<<1, 512, 0, stream>>>(part, nb);
    k_scan3<<<nb, THREADS, 0, stream>>>(offs, part, N);
    k_scatter<<<(E + THREADS - 1) / THREADS, THREADS, 0, stream>>>(row, col, offs, tmpc, rs, E);

    // ---- 3 GAT layers ----
    const float* xin = x;
    for (int l = 0; l < 3; ++l) {
        float* xout = (l == 1) ? xb1 : xb0;
        k_gemm_att<<<(N + 63) / 64, THREADS, 0, stream>>>(
            xin, Ws + (size_t)l * 16384, fold + (size_t)l * 512, h, a_s, a_d, N);
        k_alpha<<<(N + THREADS - 1) / THREADS, THREADS, 0, stream>>>(
            rs, offs, hist, a_s, a_d, alpha, N);
        k_gat<<<((size_t)N * 64 + THREADS - 1) / THREADS, THREADS, 0, stream>>>(
            rs, offs, hist, alpha, h,
            bn_gamma + l * 64, bn_beta + l * 64, bn_mean + l * 64, bn_var + l * 64,
            (l < 2) ? 1 : 0, xout, N);
        xin = xout;
    }

    // ---- pool + fc ----
    hipMemsetAsync(sums, 0, (size_t)G * 64 * 4, stream);
    hipMemsetAsync(cnt, 0, (size_t)G * 4, stream);
    int pool_waves = (N + POOL_CHUNK - 1) / POOL_CHUNK;
    k_pool<<<((size_t)pool_waves * 64 + THREADS - 1) / THREADS, THREADS, 0, stream>>>(
        xin, batch, sums, cnt, N);
    k_fc<<<(G + THREADS - 1) / THREADS, THREADS, 0, stream>>>(
        sums, cnt, fc_w, fc_b, (float*)d_out, G);
}